// Round 4
// baseline (324.313 us; speedup 1.0000x reference)
//
#include <hip/hip_runtime.h>
#include <math.h>

#define D 512
#define H 500
#define NSPAN 256
#define KCON 1024
#define L 64
#define RT 16             // rows per k_scores block
#define NCHUNK 5          // ceil(65/16)
#define HP 504            // ht row stride (floats); 2016 B rows, 16B-aligned

// ---- column-GEMM core: thread owns ONE output column (stride WS), NR rows.
// K = NG*4 k-values, weight groups of 4 double-buffered (wa/wb).
// x0: LDS tile, row stride XS floats; reads are wave-uniform float4 broadcasts.
template <int K, int WS, int NR, int XS>
__device__ __forceinline__ void col_gemm(const float* __restrict__ Wcol,
                                         const float* __restrict__ x0,
                                         float* __restrict__ acc) {
    constexpr int NG = K / 4;
    float wa[4], wb[4];
    #pragma unroll
    for (int r = 0; r < NR; ++r) acc[r] = 0.f;
    #pragma unroll
    for (int i = 0; i < 4; ++i) wa[i] = Wcol[i * WS];
    int g = 0;
    #pragma unroll 1
    for (; g + 2 < NG; g += 2) {
        int k = g * 4;
        #pragma unroll
        for (int i = 0; i < 4; ++i) wb[i] = Wcol[(k + 4 + i) * WS];
        #pragma unroll
        for (int r = 0; r < NR; ++r) {
            float4 hv = *(const float4*)&x0[r * XS + k];
            acc[r] = fmaf(hv.x, wa[0], acc[r]);
            acc[r] = fmaf(hv.y, wa[1], acc[r]);
            acc[r] = fmaf(hv.z, wa[2], acc[r]);
            acc[r] = fmaf(hv.w, wa[3], acc[r]);
        }
        #pragma unroll
        for (int i = 0; i < 4; ++i) wa[i] = Wcol[(k + 8 + i) * WS];
        #pragma unroll
        for (int r = 0; r < NR; ++r) {
            float4 hv = *(const float4*)&x0[r * XS + k + 4];
            acc[r] = fmaf(hv.x, wb[0], acc[r]);
            acc[r] = fmaf(hv.y, wb[1], acc[r]);
            acc[r] = fmaf(hv.z, wb[2], acc[r]);
            acc[r] = fmaf(hv.w, wb[3], acc[r]);
        }
    }
    if (NG % 2 == 0) {
        int k = (NG - 2) * 4;
        #pragma unroll
        for (int i = 0; i < 4; ++i) wb[i] = Wcol[(k + 4 + i) * WS];
        #pragma unroll
        for (int r = 0; r < NR; ++r) {
            float4 hv = *(const float4*)&x0[r * XS + k];
            acc[r] = fmaf(hv.x, wa[0], acc[r]);
            acc[r] = fmaf(hv.y, wa[1], acc[r]);
            acc[r] = fmaf(hv.z, wa[2], acc[r]);
            acc[r] = fmaf(hv.w, wa[3], acc[r]);
        }
        #pragma unroll
        for (int r = 0; r < NR; ++r) {
            float4 hv = *(const float4*)&x0[r * XS + k + 4];
            acc[r] = fmaf(hv.x, wb[0], acc[r]);
            acc[r] = fmaf(hv.y, wb[1], acc[r]);
            acc[r] = fmaf(hv.z, wb[2], acc[r]);
            acc[r] = fmaf(hv.w, wb[3], acc[r]);
        }
    } else {
        int k = (NG - 1) * 4;
        #pragma unroll
        for (int r = 0; r < NR; ++r) {
            float4 hv = *(const float4*)&x0[r * XS + k];
            acc[r] = fmaf(hv.x, wa[0], acc[r]);
            acc[r] = fmaf(hv.y, wa[1], acc[r]);
            acc[r] = fmaf(hv.z, wa[2], acc[r]);
            acc[r] = fmaf(hv.w, wa[3], acc[r]);
        }
    }
}

// ------- Kernel 1: fused sentinel + span/know/sent W1-half GEMMs -----------
// 384 blocks x 4 rows, column-split: weights read exactly once per block.
// b<64: span@W1a; b<320: know@W1b; b>=320: sentinel (span@Ws relu, then @W1b).
__global__ __launch_bounds__(512, 4) void k_parts(
    const float* __restrict__ span, const float* __restrict__ know,
    const float* __restrict__ Ws, const float* __restrict__ bs,
    const float* __restrict__ W1,
    float* __restrict__ sentinel, float* __restrict__ span_part,
    float* __restrict__ know_part, float* __restrict__ sent_part) {
    __shared__ __align__(16) float xt[4][D];
    int b = blockIdx.x, tid = threadIdx.x;
    const float* xbase;
    int mode, r0;
    if (b < 64) { mode = 0; r0 = b * 4; xbase = span + r0 * D; }
    else if (b < 320) { mode = 1; r0 = (b - 64) * 4; xbase = know + r0 * D; }
    else { mode = 2; r0 = (b - 320) * 4; xbase = span + r0 * D; }
    #pragma unroll
    for (int r = 0; r < 4; ++r) xt[r][tid] = xbase[r * D + tid];
    __syncthreads();

    int j = tid;
    int jc = (j < H) ? j : (H - 1);
    float acc[4];
    if (mode == 2) {
        // GEMM1: relu(span @ Ws + bs) -> sentinel, restage to LDS
        col_gemm<D, D, 4, D>(Ws + j, &xt[0][0], acc);
        float bv = bs[j];
        float v[4];
        #pragma unroll
        for (int r = 0; r < 4; ++r) {
            v[r] = fmaxf(acc[r] + bv, 0.f);
            sentinel[(r0 + r) * D + j] = v[r];
        }
        __syncthreads();
        #pragma unroll
        for (int r = 0; r < 4; ++r) xt[r][j] = v[r];
        __syncthreads();
        col_gemm<D, H, 4, D>(W1 + (size_t)D * H + jc, &xt[0][0], acc);
        if (j < H) {
            #pragma unroll
            for (int r = 0; r < 4; ++r) sent_part[(r0 + r) * H + j] = acc[r];
        }
    } else {
        const float* Wb = (mode == 0) ? W1 : (W1 + (size_t)D * H);
        float* out = (mode == 0) ? span_part : know_part;
        col_gemm<D, H, 4, D>(Wb + jc, &xt[0][0], acc);
        if (j < H) {
            #pragma unroll
            for (int r = 0; r < 4; ++r) out[(r0 + r) * H + j] = acc[r];
        }
    }
}

// ---- Kernel 2: scores for ACTIVE positions, 16-row chunks, column-split ----
// Thread j owns score-column j for all 16 rows; W2 read ONCE per block (1 MB).
__global__ __launch_bounds__(512, 4) void k_scores(
    const int* __restrict__ s2c, const int* __restrict__ lengths,
    const float* __restrict__ span_part, const float* __restrict__ know_part,
    const float* __restrict__ sent_part, const float* __restrict__ b1,
    const float* __restrict__ W2, const float* __restrict__ b2,
    const float* __restrict__ W3, const float* __restrict__ b3,
    float* __restrict__ scores) {
    int n = blockIdx.x;
    int V = lengths[n];
    if (V < 1) V = 1;
    int R = V + 1;
    int r0 = blockIdx.y * RT;
    if (r0 >= R) return;
    int rc = min(RT, R - r0);

    __shared__ __align__(16) float ht[RT][HP];  // 32256 B
    __shared__ float red[8][RT];                // 512 B

    int tid = threadIdx.x;
    if (tid < H) {
        float sb = span_part[n * H + tid] + b1[tid];
        #pragma unroll
        for (int r = 0; r < RT; ++r) {
            int row = r0 + r;
            int ci = s2c[n * L + min(row, V - 1)];
            const float* src = (row < V) ? (know_part + ci * H) : (sent_part + n * H);
            ht[r][tid] = (r < rc) ? fmaxf(sb + src[tid], 0.f) : 0.f;
        }
    }
    __syncthreads();

    int j = tid;
    int jc = (j < H) ? j : (H - 1);
    float acc[RT];
    col_gemm<H, H, RT, HP>(W2 + jc, &ht[0][0], acc);

    float b2j = b2[jc];
    float w3j = (j < H) ? W3[jc] : 0.f;
    int wv = tid >> 6, lane = tid & 63;
    #pragma unroll
    for (int r = 0; r < RT; ++r) {
        float v = fmaxf(acc[r] + b2j, 0.f) * w3j;
        #pragma unroll
        for (int off = 32; off > 0; off >>= 1) v += __shfl_down(v, off, 64);
        if (lane == 0) red[wv][r] = v;
    }
    __syncthreads();
    if (tid < rc) {
        float s = b3[0];
        #pragma unroll
        for (int w = 0; w < 8; ++w) s += red[w][tid];
        int ar = r0 + tid;
        int lpos = (ar < V) ? ar : L;
        scores[n * (L + 1) + lpos] = s;
    }
}

// -------- Kernel 3: masked softmax + probs out + feature gather ------------
// 64 blocks x 512 threads; 4 spans/block, 128 float4-threads per span.
__global__ __launch_bounds__(512) void k_out(
    const int* __restrict__ s2c, const int* __restrict__ lengths,
    const float* __restrict__ scores, const float* __restrict__ know,
    const float* __restrict__ sentinel, float* __restrict__ out_features,
    float* __restrict__ out_probs) {
    int sub = threadIdx.x >> 7, t = threadIdx.x & 127;
    int n = blockIdx.x * 4 + sub;
    __shared__ float p[4][L + 1];
    __shared__ int idx[4][L];
    int V = lengths[n];
    if (V < 1) V = 1;
    if (t < L) idx[sub][t] = s2c[n * L + t];
    if (t == 0) {
        const float* srow = scores + n * (L + 1);
        float m = srow[L];
        for (int l = 0; l < V; ++l) m = fmaxf(m, srow[l]);
        float sum = 0.f;
        for (int l = 0; l < V; ++l) { float e = expf(srow[l] - m); p[sub][l] = e; sum += e; }
        for (int l = V; l < L; ++l) p[sub][l] = 0.f;
        float es = expf(srow[L] - m); p[sub][L] = es; sum += es;
        float inv = 1.f / sum;
        for (int l = 0; l <= L; ++l) p[sub][l] *= inv;
    }
    __syncthreads();
    if (t <= L) out_probs[n * (L + 1) + t] = p[sub][t];
    const float4* kn = (const float4*)know;
    float4 acc;
    {
        float ps = p[sub][L];
        float4 sv = ((const float4*)sentinel)[n * 128 + t];
        acc.x = ps * sv.x; acc.y = ps * sv.y; acc.z = ps * sv.z; acc.w = ps * sv.w;
    }
    int l = 0;
    for (; l + 2 <= V; l += 2) {
        float p0 = p[sub][l], p1 = p[sub][l + 1];
        float4 v0 = kn[idx[sub][l] * 128 + t];
        float4 v1 = kn[idx[sub][l + 1] * 128 + t];
        acc.x = fmaf(p0, v0.x, acc.x); acc.y = fmaf(p0, v0.y, acc.y);
        acc.z = fmaf(p0, v0.z, acc.z); acc.w = fmaf(p0, v0.w, acc.w);
        acc.x = fmaf(p1, v1.x, acc.x); acc.y = fmaf(p1, v1.y, acc.y);
        acc.z = fmaf(p1, v1.z, acc.z); acc.w = fmaf(p1, v1.w, acc.w);
    }
    if (l < V) {
        float p0 = p[sub][l];
        float4 v0 = kn[idx[sub][l] * 128 + t];
        acc.x = fmaf(p0, v0.x, acc.x); acc.y = fmaf(p0, v0.y, acc.y);
        acc.z = fmaf(p0, v0.z, acc.z); acc.w = fmaf(p0, v0.w, acc.w);
    }
    ((float4*)out_features)[n * 128 + t] = acc;
}

extern "C" void kernel_launch(void* const* d_in, const int* in_sizes, int n_in,
                              void* d_out, int out_size, void* d_ws, size_t ws_size,
                              hipStream_t stream) {
    const float* span = (const float*)d_in[0];   // (256, 512)
    const float* know = (const float*)d_in[1];   // (1024, 512)
    const int* s2c = (const int*)d_in[2];        // (256, 64)
    const int* lengths = (const int*)d_in[3];    // (256,)
    const float* Ws = (const float*)d_in[4];     // (512, 512)
    const float* bs = (const float*)d_in[5];     // (512,)
    const float* W1 = (const float*)d_in[6];     // (1024, 500)
    const float* b1 = (const float*)d_in[7];     // (500,)
    const float* W2 = (const float*)d_in[8];     // (500, 500)
    const float* b2 = (const float*)d_in[9];     // (500,)
    const float* W3 = (const float*)d_in[10];    // (500, 1)
    const float* b3 = (const float*)d_in[11];    // (1,)

    float* ws = (float*)d_ws;
    float* sentinel = ws;                       // 256*512
    float* span_part = sentinel + NSPAN * D;    // 256*500
    float* know_part = span_part + NSPAN * H;   // 1024*500
    float* sent_part = know_part + KCON * H;    // 256*500
    float* scores = sent_part + NSPAN * H;      // 256*65

    float* out_features = (float*)d_out;             // 256*512
    float* out_probs = out_features + NSPAN * D;     // 256*65

    k_parts<<<384, 512, 0, stream>>>(span, know, Ws, bs, W1, sentinel,
                                     span_part, know_part, sent_part);
    k_scores<<<dim3(NSPAN, NCHUNK), 512, 0, stream>>>(
        s2c, lengths, span_part, know_part, sent_part, b1, W2, b2, W3, b3, scores);
    k_out<<<NSPAN / 4, 512, 0, stream>>>(s2c, lengths, scores, know, sentinel,
                                         out_features, out_probs);
}

// Round 5
// 283.180 us; speedup vs baseline: 1.1453x; 1.1453x over previous
//
#include <hip/hip_runtime.h>
#include <math.h>

#define D 512
#define H 500
#define NSPAN 256
#define KCON 1024
#define L 64
#define RT 16                 // rows per k_scores tile
#define MMAX (NSPAN * (L + 1))  // 16640 flat-row upper bound

// ---- column-pair GEMM core -------------------------------------------------
// Thread owns cols (j0, j0+1) for NR rows. Weights W[k*ws + j0] (float2,
// coalesced, read once per block). x0: LDS tile [NR][xs], rows 16B-aligned;
// reads are wave-uniform float4 broadcasts: NR b128 per 4k vs NR*8 FMA-inst.
template <int K, int NR>
__device__ __forceinline__ void col2_gemm(const float* __restrict__ W, int ws,
                                          int j0, const float* __restrict__ x0,
                                          int xs, float2* __restrict__ acc) {
    constexpr int NG = K / 4;
    float2 wa[4], wb[4];
    #pragma unroll
    for (int r = 0; r < NR; ++r) { acc[r].x = 0.f; acc[r].y = 0.f; }
    #pragma unroll
    for (int i = 0; i < 4; ++i) wa[i] = *(const float2*)&W[i * ws + j0];
    #pragma unroll 1
    for (int g = 0; g + 1 < NG; ++g) {
        #pragma unroll
        for (int i = 0; i < 4; ++i)
            wb[i] = *(const float2*)&W[((g + 1) * 4 + i) * ws + j0];
        int k = g * 4;
        #pragma unroll
        for (int r = 0; r < NR; ++r) {
            float4 hv = *(const float4*)&x0[r * xs + k];
            acc[r].x = fmaf(hv.x, wa[0].x, acc[r].x); acc[r].y = fmaf(hv.x, wa[0].y, acc[r].y);
            acc[r].x = fmaf(hv.y, wa[1].x, acc[r].x); acc[r].y = fmaf(hv.y, wa[1].y, acc[r].y);
            acc[r].x = fmaf(hv.z, wa[2].x, acc[r].x); acc[r].y = fmaf(hv.z, wa[2].y, acc[r].y);
            acc[r].x = fmaf(hv.w, wa[3].x, acc[r].x); acc[r].y = fmaf(hv.w, wa[3].y, acc[r].y);
        }
        #pragma unroll
        for (int i = 0; i < 4; ++i) wa[i] = wb[i];
    }
    {   // tail group (NG-1), weights already in wa
        int k = (NG - 1) * 4;
        #pragma unroll
        for (int r = 0; r < NR; ++r) {
            float4 hv = *(const float4*)&x0[r * xs + k];
            acc[r].x = fmaf(hv.x, wa[0].x, acc[r].x); acc[r].y = fmaf(hv.x, wa[0].y, acc[r].y);
            acc[r].x = fmaf(hv.y, wa[1].x, acc[r].x); acc[r].y = fmaf(hv.y, wa[1].y, acc[r].y);
            acc[r].x = fmaf(hv.z, wa[2].x, acc[r].x); acc[r].y = fmaf(hv.z, wa[2].y, acc[r].y);
            acc[r].x = fmaf(hv.w, wa[3].x, acc[r].x); acc[r].y = fmaf(hv.w, wa[3].y, acc[r].y);
        }
    }
}

// ------- Kernel 1: parts GEMMs + sentinel + flat-row planner ---------------
// 193 blocks, 512 thr. b<32: span@W1a(+b1)->spanb1; b<160: know@W1b->parts;
// b<192: sentinel (relu(span@Ws+bs) -> sentinel buf, restage, @W1b ->
// parts[1024+]); b==192: planner (scan lengths -> row_map + M).
__global__ __launch_bounds__(512, 4) void k_parts(
    const float* __restrict__ span, const float* __restrict__ know,
    const int* __restrict__ s2c, const int* __restrict__ lengths,
    const float* __restrict__ Ws, const float* __restrict__ bs,
    const float* __restrict__ W1, const float* __restrict__ b1,
    float* __restrict__ spanb1, float* __restrict__ parts,
    float* __restrict__ sentinel, int* __restrict__ row_map,
    int* __restrict__ Mptr) {
    int b = blockIdx.x, tid = threadIdx.x;

    if (b == 192) {   // ---- planner ----
        __shared__ int sc[NSPAN];
        int R = 0;
        if (tid < NSPAN) {
            int V = lengths[tid];
            if (V < 1) V = 1;
            R = V + 1;
            sc[tid] = R;
        }
        __syncthreads();
        for (int s = 1; s < NSPAN; s <<= 1) {
            int v = 0;
            if (tid < NSPAN && tid >= s) v = sc[tid - s];
            __syncthreads();
            if (tid < NSPAN) sc[tid] += v;
            __syncthreads();
        }
        if (tid < NSPAN) {
            int start = sc[tid] - R;
            int V = R - 1;
            for (int l = 0; l < V; ++l)
                row_map[start + l] = (s2c[tid * L + l] << 16) | (tid << 8) | l;
            row_map[start + V] = ((KCON + tid) << 16) | (tid << 8) | L;
            if (tid == NSPAN - 1) Mptr[0] = sc[NSPAN - 1];
        }
        return;
    }

    __shared__ __align__(16) float xt[8][D];   // 16 KB
    const float* xbase;
    int mode, r0;
    if (b < 32) { mode = 0; r0 = b * 8; xbase = span + r0 * D; }
    else if (b < 160) { mode = 1; r0 = (b - 32) * 8; xbase = know + r0 * D; }
    else { mode = 2; r0 = (b - 160) * 8; xbase = span + r0 * D; }
    #pragma unroll
    for (int r = 0; r < 4; ++r)
        xt[r * 2 + (tid >> 8)][tid & 255] = xbase[(r * 2 + (tid >> 8)) * D + (tid & 255)];
    // second half of each row (cols 256..511)
    #pragma unroll
    for (int r = 0; r < 4; ++r)
        xt[r * 2 + (tid >> 8)][256 + (tid & 255)] =
            xbase[(r * 2 + (tid >> 8)) * D + 256 + (tid & 255)];
    __syncthreads();

    int jt = tid & 255, q = tid >> 8;          // q: 2 row-halves of 4
    int j0 = jt * 2;
    float2 acc[4];
    const float* x0 = &xt[q * 4][0];

    if (mode == 2) {
        // GEMM1: relu(span @ Ws + bs), all 512 cols active
        col2_gemm<D, 4>(Ws, D, j0, x0, D, acc);
        float2 bv = *(const float2*)&bs[j0];
        float2 v[4];
        #pragma unroll
        for (int r = 0; r < 4; ++r) {
            v[r].x = fmaxf(acc[r].x + bv.x, 0.f);
            v[r].y = fmaxf(acc[r].y + bv.y, 0.f);
            *(float2*)&sentinel[(r0 + q * 4 + r) * D + j0] = v[r];
        }
        __syncthreads();   // GEMM1's xt reads done
        #pragma unroll
        for (int r = 0; r < 4; ++r) *(float2*)&xt[q * 4 + r][j0] = v[r];
        __syncthreads();
        int jc0 = (j0 < H) ? j0 : 0;
        col2_gemm<D, 4>(W1 + (size_t)D * H, H, jc0, x0, D, acc);
        if (j0 < H) {
            #pragma unroll
            for (int r = 0; r < 4; ++r)
                *(float2*)&parts[(size_t)(KCON + r0 + q * 4 + r) * H + j0] = acc[r];
        }
    } else {
        int jc0 = (j0 < H) ? j0 : 0;
        const float* Wb = (mode == 0) ? W1 : (W1 + (size_t)D * H);
        col2_gemm<D, 4>(Wb, H, jc0, x0, D, acc);
        if (j0 < H) {
            if (mode == 0) {
                float2 b1v = *(const float2*)&b1[j0];
                #pragma unroll
                for (int r = 0; r < 4; ++r) {
                    float2 o; o.x = acc[r].x + b1v.x; o.y = acc[r].y + b1v.y;
                    *(float2*)&spanb1[(size_t)(r0 + q * 4 + r) * H + j0] = o;
                }
            } else {
                #pragma unroll
                for (int r = 0; r < 4; ++r)
                    *(float2*)&parts[(size_t)(r0 + q * 4 + r) * H + j0] = acc[r];
            }
        }
    }
}

// ---- Kernel 2: flat balanced score GEMM: 16 uniform rows per block --------
// 256 thr; thread owns 2 cols x 16 rows; W2 read exactly once per block.
__global__ __launch_bounds__(256, 4) void k_scores(
    const int* __restrict__ row_map, const int* __restrict__ Mptr,
    const float* __restrict__ spanb1, const float* __restrict__ parts,
    const float* __restrict__ W2, const float* __restrict__ b2,
    const float* __restrict__ W3, const float* __restrict__ b3,
    float* __restrict__ scores) {
    int tid = threadIdx.x;
    int t0 = blockIdx.x * RT;
    int M = Mptr[0];
    if (t0 >= M) return;
    int rc = min(RT, M - t0);

    __shared__ __align__(16) float ht[RT][H];  // 32000 B
    __shared__ float red[4][RT];
    __shared__ int rinfo[RT];
    if (tid < RT) rinfo[tid] = row_map[t0 + min(tid, rc - 1)];
    __syncthreads();

    // stage h1 rows: relu(spanb1[n] + parts[srcrow])  (b1 pre-folded)
    #pragma unroll 4
    for (int r = 0; r < RT; ++r) {
        int e = rinfo[r];
        const float* src = parts + (size_t)(e >> 16) * H;
        const float* spn = spanb1 + (size_t)((e >> 8) & 0xff) * H;
        float v0 = (r < rc) ? fmaxf(spn[tid] + src[tid], 0.f) : 0.f;
        ht[r][tid] = v0;
        if (tid + 256 < H) {
            float v1 = (r < rc) ? fmaxf(spn[tid + 256] + src[tid + 256], 0.f) : 0.f;
            ht[r][tid + 256] = v1;
        }
    }
    __syncthreads();

    int j0 = tid * 2;
    bool active = (j0 < H);       // 250 working threads
    int jc0 = active ? j0 : 0;
    float2 acc[RT];
    col2_gemm<H, RT>(W2, H, jc0, &ht[0][0], H, acc);

    float b2a = b2[jc0], b2b = b2[jc0 + 1];
    float w3a = active ? W3[jc0] : 0.f;
    float w3b = active ? W3[jc0 + 1] : 0.f;
    int wv = tid >> 6, lane = tid & 63;
    #pragma unroll
    for (int r = 0; r < RT; ++r) {
        float v = fmaxf(acc[r].x + b2a, 0.f) * w3a
                + fmaxf(acc[r].y + b2b, 0.f) * w3b;
        #pragma unroll
        for (int off = 32; off > 0; off >>= 1) v += __shfl_down(v, off, 64);
        if (lane == 0) red[wv][r] = v;
    }
    __syncthreads();
    if (tid < rc) {
        int e = rinfo[tid];
        int n = (e >> 8) & 0xff, lpos = e & 0xff;
        scores[n * (L + 1) + lpos] =
            red[0][tid] + red[1][tid] + red[2][tid] + red[3][tid] + b3[0];
    }
}

// -------- Kernel 3: masked softmax + probs out + feature gather ------------
__global__ __launch_bounds__(512) void k_out(
    const int* __restrict__ s2c, const int* __restrict__ lengths,
    const float* __restrict__ scores, const float* __restrict__ know,
    const float* __restrict__ sentinel, float* __restrict__ out_features,
    float* __restrict__ out_probs) {
    int sub = threadIdx.x >> 7, t = threadIdx.x & 127;
    int n = blockIdx.x * 4 + sub;
    __shared__ float p[4][L + 1];
    __shared__ int idx[4][L];
    int V = lengths[n];
    if (V < 1) V = 1;
    if (t < L) idx[sub][t] = s2c[n * L + t];
    if (t == 0) {
        const float* srow = scores + n * (L + 1);
        float m = srow[L];
        for (int l = 0; l < V; ++l) m = fmaxf(m, srow[l]);
        float sum = 0.f;
        for (int l = 0; l < V; ++l) { float e = expf(srow[l] - m); p[sub][l] = e; sum += e; }
        for (int l = V; l < L; ++l) p[sub][l] = 0.f;
        float es = expf(srow[L] - m); p[sub][L] = es; sum += es;
        float inv = 1.f / sum;
        for (int l = 0; l <= L; ++l) p[sub][l] *= inv;
    }
    __syncthreads();
    if (t <= L) out_probs[n * (L + 1) + t] = p[sub][t];
    const float4* kn = (const float4*)know;
    float4 acc;
    {
        float ps = p[sub][L];
        float4 sv = ((const float4*)sentinel)[n * 128 + t];
        acc.x = ps * sv.x; acc.y = ps * sv.y; acc.z = ps * sv.z; acc.w = ps * sv.w;
    }
    int l = 0;
    for (; l + 2 <= V; l += 2) {
        float p0 = p[sub][l], p1 = p[sub][l + 1];
        float4 v0 = kn[idx[sub][l] * 128 + t];
        float4 v1 = kn[idx[sub][l + 1] * 128 + t];
        acc.x = fmaf(p0, v0.x, acc.x); acc.y = fmaf(p0, v0.y, acc.y);
        acc.z = fmaf(p0, v0.z, acc.z); acc.w = fmaf(p0, v0.w, acc.w);
        acc.x = fmaf(p1, v1.x, acc.x); acc.y = fmaf(p1, v1.y, acc.y);
        acc.z = fmaf(p1, v1.z, acc.z); acc.w = fmaf(p1, v1.w, acc.w);
    }
    if (l < V) {
        float p0 = p[sub][l];
        float4 v0 = kn[idx[sub][l] * 128 + t];
        acc.x = fmaf(p0, v0.x, acc.x); acc.y = fmaf(p0, v0.y, acc.y);
        acc.z = fmaf(p0, v0.z, acc.z); acc.w = fmaf(p0, v0.w, acc.w);
    }
    ((float4*)out_features)[n * 128 + t] = acc;
}

extern "C" void kernel_launch(void* const* d_in, const int* in_sizes, int n_in,
                              void* d_out, int out_size, void* d_ws, size_t ws_size,
                              hipStream_t stream) {
    const float* span = (const float*)d_in[0];   // (256, 512)
    const float* know = (const float*)d_in[1];   // (1024, 512)
    const int* s2c = (const int*)d_in[2];        // (256, 64)
    const int* lengths = (const int*)d_in[3];    // (256,)
    const float* Ws = (const float*)d_in[4];     // (512, 512)
    const float* bs = (const float*)d_in[5];     // (512,)
    const float* W1 = (const float*)d_in[6];     // (1024, 500)
    const float* b1 = (const float*)d_in[7];     // (500,)
    const float* W2 = (const float*)d_in[8];     // (500, 500)
    const float* b2 = (const float*)d_in[9];     // (500,)
    const float* W3 = (const float*)d_in[10];    // (500, 1)
    const float* b3 = (const float*)d_in[11];    // (1,)

    float* ws = (float*)d_ws;
    float* spanb1 = ws;                               // 256*500
    float* parts = spanb1 + NSPAN * H;                // 1280*500 (know | sent)
    float* sentinel = parts + (KCON + NSPAN) * H;     // 256*512
    float* scores = sentinel + NSPAN * D;             // 256*65
    int* row_map = (int*)(scores + NSPAN * (L + 1));  // 16640
    int* Mptr = row_map + MMAX;                       // 1

    float* out_features = (float*)d_out;              // 256*512
    float* out_probs = out_features + NSPAN * D;      // 256*65

    k_parts<<<193, 512, 0, stream>>>(span, know, s2c, lengths, Ws, bs, W1, b1,
                                     spanb1, parts, sentinel, row_map, Mptr);
    k_scores<<<MMAX / RT, 256, 0, stream>>>(row_map, Mptr, spanb1, parts,
                                            W2, b2, W3, b3, scores);
    k_out<<<NSPAN / 4, 512, 0, stream>>>(s2c, lengths, scores, know, sentinel,
                                         out_features, out_probs);
}

// Round 6
// 200.484 us; speedup vs baseline: 1.6177x; 1.4125x over previous
//
#include <hip/hip_runtime.h>
#include <math.h>
#include <stdint.h>

#define D 512
#define H 500
#define NSPAN 256
#define KCON 1024
#define L 64
#define RT 16                   // flat rows per k_scores block
#define MMAX (NSPAN * (L + 1))  // 16640 flat-row upper bound

typedef __attribute__((ext_vector_type(8))) short short8;
typedef __attribute__((ext_vector_type(4))) float floatx4;

__device__ __forceinline__ short f2bf(float f) {   // RNE f32->bf16
    unsigned u = __builtin_bit_cast(unsigned, f);
    return (short)((u + 0x7fffu + ((u >> 16) & 1u)) >> 16);
}

// ---- fp32 column-pair GEMM core (k_parts) ---------------------------------
template <int K, int NR>
__device__ __forceinline__ void col2_gemm(const float* __restrict__ W, int ws,
                                          int j0, const float* __restrict__ x0,
                                          int xs, float2* __restrict__ acc) {
    constexpr int NG = K / 4;
    float2 wa[4], wb[4];
    #pragma unroll
    for (int r = 0; r < NR; ++r) { acc[r].x = 0.f; acc[r].y = 0.f; }
    #pragma unroll
    for (int i = 0; i < 4; ++i) wa[i] = *(const float2*)&W[i * ws + j0];
    #pragma unroll 1
    for (int g = 0; g + 1 < NG; ++g) {
        #pragma unroll
        for (int i = 0; i < 4; ++i)
            wb[i] = *(const float2*)&W[((g + 1) * 4 + i) * ws + j0];
        int k = g * 4;
        #pragma unroll
        for (int r = 0; r < NR; ++r) {
            float4 hv = *(const float4*)&x0[r * xs + k];
            acc[r].x = fmaf(hv.x, wa[0].x, acc[r].x); acc[r].y = fmaf(hv.x, wa[0].y, acc[r].y);
            acc[r].x = fmaf(hv.y, wa[1].x, acc[r].x); acc[r].y = fmaf(hv.y, wa[1].y, acc[r].y);
            acc[r].x = fmaf(hv.z, wa[2].x, acc[r].x); acc[r].y = fmaf(hv.z, wa[2].y, acc[r].y);
            acc[r].x = fmaf(hv.w, wa[3].x, acc[r].x); acc[r].y = fmaf(hv.w, wa[3].y, acc[r].y);
        }
        #pragma unroll
        for (int i = 0; i < 4; ++i) wa[i] = wb[i];
    }
    {
        int k = (NG - 1) * 4;
        #pragma unroll
        for (int r = 0; r < NR; ++r) {
            float4 hv = *(const float4*)&x0[r * xs + k];
            acc[r].x = fmaf(hv.x, wa[0].x, acc[r].x); acc[r].y = fmaf(hv.x, wa[0].y, acc[r].y);
            acc[r].x = fmaf(hv.y, wa[1].x, acc[r].x); acc[r].y = fmaf(hv.y, wa[1].y, acc[r].y);
            acc[r].x = fmaf(hv.z, wa[2].x, acc[r].x); acc[r].y = fmaf(hv.z, wa[2].y, acc[r].y);
            acc[r].x = fmaf(hv.w, wa[3].x, acc[r].x); acc[r].y = fmaf(hv.w, wa[3].y, acc[r].y);
        }
    }
}

// ------- Kernel 1: parts GEMMs + sentinel + planner + W2->bf16 swizzle -----
// b<32: span@W1a(+b1); b<160: know@W1b; b<192: sentinel chain; b==192:
// planner; b in [193,257): W2 -> bf16 B-fragment-swizzled copy.
__global__ __launch_bounds__(512, 4) void k_parts(
    const float* __restrict__ span, const float* __restrict__ know,
    const int* __restrict__ s2c, const int* __restrict__ lengths,
    const float* __restrict__ Ws, const float* __restrict__ bs,
    const float* __restrict__ W1, const float* __restrict__ b1,
    const float* __restrict__ W2,
    float* __restrict__ spanb1, float* __restrict__ parts,
    float* __restrict__ sentinel, int* __restrict__ row_map,
    int* __restrict__ Mptr, short* __restrict__ W2bf) {
    int b = blockIdx.x, tid = threadIdx.x;

    if (b >= 193) {   // ---- W2 bf16 swizzle: slot = one short8 (8 k, 1 n) ----
        int s = (b - 193) * 512 + tid;          // [0, 32768)
        int kq = s & 3, n = (s >> 2) & 511, kb = s >> 11;
        int k0 = kb * 32 + kq * 8;
        short8 v8;
        #pragma unroll
        for (int i = 0; i < 8; ++i) {
            int k = k0 + i;
            float v = (k < H && n < H) ? W2[k * H + n] : 0.f;
            v8[i] = f2bf(v);
        }
        ((short8*)W2bf)[s] = v8;
        return;
    }

    if (b == 192) {   // ---- planner ----
        __shared__ int sc[NSPAN];
        int R = 0;
        if (tid < NSPAN) {
            int V = lengths[tid];
            if (V < 1) V = 1;
            R = V + 1;
            sc[tid] = R;
        }
        __syncthreads();
        for (int s = 1; s < NSPAN; s <<= 1) {
            int v = 0;
            if (tid < NSPAN && tid >= s) v = sc[tid - s];
            __syncthreads();
            if (tid < NSPAN) sc[tid] += v;
            __syncthreads();
        }
        if (tid < NSPAN) {
            int start = sc[tid] - R;
            int V = R - 1;
            for (int l = 0; l < V; ++l)
                row_map[start + l] = (s2c[tid * L + l] << 16) | (tid << 8) | l;
            row_map[start + V] = ((KCON + tid) << 16) | (tid << 8) | L;
            if (tid == NSPAN - 1) Mptr[0] = sc[NSPAN - 1];
        }
        return;
    }

    __shared__ __align__(16) float xt[8][D];   // 16 KB
    const float* xbase;
    int mode, r0;
    if (b < 32) { mode = 0; r0 = b * 8; xbase = span + r0 * D; }
    else if (b < 160) { mode = 1; r0 = (b - 32) * 8; xbase = know + r0 * D; }
    else { mode = 2; r0 = (b - 160) * 8; xbase = span + r0 * D; }
    #pragma unroll
    for (int r = 0; r < 4; ++r)
        xt[r * 2 + (tid >> 8)][tid & 255] = xbase[(r * 2 + (tid >> 8)) * D + (tid & 255)];
    #pragma unroll
    for (int r = 0; r < 4; ++r)
        xt[r * 2 + (tid >> 8)][256 + (tid & 255)] =
            xbase[(r * 2 + (tid >> 8)) * D + 256 + (tid & 255)];
    __syncthreads();

    int jt = tid & 255, q = tid >> 8;
    int j0 = jt * 2;
    float2 acc[4];
    const float* x0 = &xt[q * 4][0];

    if (mode == 2) {
        col2_gemm<D, 4>(Ws, D, j0, x0, D, acc);
        float2 bv = *(const float2*)&bs[j0];
        float2 v[4];
        #pragma unroll
        for (int r = 0; r < 4; ++r) {
            v[r].x = fmaxf(acc[r].x + bv.x, 0.f);
            v[r].y = fmaxf(acc[r].y + bv.y, 0.f);
            *(float2*)&sentinel[(r0 + q * 4 + r) * D + j0] = v[r];
        }
        __syncthreads();
        #pragma unroll
        for (int r = 0; r < 4; ++r) *(float2*)&xt[q * 4 + r][j0] = v[r];
        __syncthreads();
        int jc0 = (j0 < H) ? j0 : 0;
        col2_gemm<D, 4>(W1 + (size_t)D * H, H, jc0, x0, D, acc);
        if (j0 < H) {
            #pragma unroll
            for (int r = 0; r < 4; ++r)
                *(float2*)&parts[(size_t)(KCON + r0 + q * 4 + r) * H + j0] = acc[r];
        }
    } else {
        int jc0 = (j0 < H) ? j0 : 0;
        const float* Wb = (mode == 0) ? W1 : (W1 + (size_t)D * H);
        col2_gemm<D, 4>(Wb, H, jc0, x0, D, acc);
        if (j0 < H) {
            if (mode == 0) {
                float2 b1v = *(const float2*)&b1[j0];
                #pragma unroll
                for (int r = 0; r < 4; ++r) {
                    float2 o; o.x = acc[r].x + b1v.x; o.y = acc[r].y + b1v.y;
                    *(float2*)&spanb1[(size_t)(r0 + q * 4 + r) * H + j0] = o;
                }
            } else {
                #pragma unroll
                for (int r = 0; r < 4; ++r)
                    *(float2*)&parts[(size_t)(r0 + q * 4 + r) * H + j0] = acc[r];
            }
        }
    }
}

// ---- Kernel 2: MFMA score GEMM: C[16 x 512] = h1[16 x 512] @ W2bf ---------
// 256 thr = 4 waves; wave handles 8 n-tiles of 16 cols. A in LDS (frag-
// swizzled bf16), B streamed from the pre-swizzled global copy (L2).
__global__ __launch_bounds__(256, 4) void k_scores(
    const int* __restrict__ row_map, const int* __restrict__ Mptr,
    const float* __restrict__ spanb1, const float* __restrict__ parts,
    const short* __restrict__ W2bf, const float* __restrict__ b2,
    const float* __restrict__ W3, const float* __restrict__ b3,
    float* __restrict__ scores) {
    int tid = threadIdx.x;
    int t0 = blockIdx.x * RT;
    int M = Mptr[0];
    if (t0 >= M) return;
    int rc = min(RT, M - t0);

    __shared__ __align__(16) short Asw[16 * 512];  // 16 KB: ((kb*16+m)*4+kq)*8+i
    __shared__ float red[4][RT];
    __shared__ int rinfo[RT];
    if (tid < RT) rinfo[tid] = row_map[t0 + min(tid, rc - 1)];
    __syncthreads();

    {   // stage h1 -> Asw: thread = (row r, k-panel kb), 32 contiguous bf16
        int r = tid >> 4, kb = tid & 15;
        int e = rinfo[r];
        const float* src = parts + (size_t)(e >> 16) * H;
        const float* spn = spanb1 + (size_t)((e >> 8) & 0xff) * H;
        short* dst = &Asw[kb * 512 + r * 32];
        int k0 = kb * 32;
        #pragma unroll
        for (int i = 0; i < 32; ++i) {
            int k = k0 + i;
            float v = (k < H) ? fmaxf(spn[k] + src[k], 0.f) : 0.f;
            dst[i] = f2bf(v);
        }
    }
    __syncthreads();

    int wv = tid >> 6, ln = tid & 63;
    int nl = ln & 15, kq = ln >> 4;
    floatx4 acc[8];
    #pragma unroll
    for (int t = 0; t < 8; ++t) acc[t] = (floatx4){0.f, 0.f, 0.f, 0.f};

    const short8* B = (const short8*)W2bf;
    int aoff = nl * 32 + kq * 8;                 // within 512-short kb panel
    int boff = wv * 8 * 64 + nl * 4 + kq;        // short8 idx within 2048/kb panel
    #pragma unroll 1
    for (int kb = 0; kb < 16; ++kb) {
        short8 a = *(const short8*)&Asw[kb * 512 + aoff];
        short8 bfr[8];
        #pragma unroll
        for (int t = 0; t < 8; ++t) bfr[t] = B[kb * 2048 + boff + t * 64];
        #pragma unroll
        for (int t = 0; t < 8; ++t)
            acc[t] = __builtin_amdgcn_mfma_f32_16x16x32_bf16(a, bfr[t], acc[t], 0, 0, 0);
    }

    // epilogue: score-row partial = sum_cols relu(h2 + b2) * W3
    float vsum[4] = {0.f, 0.f, 0.f, 0.f};
    #pragma unroll
    for (int t = 0; t < 8; ++t) {
        int col = (wv * 8 + t) * 16 + nl;
        float b2c = (col < H) ? b2[col] : 0.f;
        float w3c = (col < H) ? W3[col] : 0.f;
        #pragma unroll
        for (int r = 0; r < 4; ++r)
            vsum[r] += fmaxf(acc[t][r] + b2c, 0.f) * w3c;
    }
    #pragma unroll
    for (int r = 0; r < 4; ++r) {   // reduce over the 16 col-lanes
        float v = vsum[r];
        v += __shfl_xor(v, 1, 64);
        v += __shfl_xor(v, 2, 64);
        v += __shfl_xor(v, 4, 64);
        v += __shfl_xor(v, 8, 64);
        vsum[r] = v;
    }
    if (nl == 0) {
        #pragma unroll
        for (int r = 0; r < 4; ++r) red[wv][kq * 4 + r] = vsum[r];  // row = kq*4+r
    }
    __syncthreads();
    if (tid < rc) {
        int e = rinfo[tid];
        int n = (e >> 8) & 0xff, lpos = e & 0xff;
        scores[n * (L + 1) + lpos] =
            red[0][tid] + red[1][tid] + red[2][tid] + red[3][tid] + b3[0];
    }
}

// -------- Kernel 3: masked softmax + probs out + feature gather ------------
__global__ __launch_bounds__(512) void k_out(
    const int* __restrict__ s2c, const int* __restrict__ lengths,
    const float* __restrict__ scores, const float* __restrict__ know,
    const float* __restrict__ sentinel, float* __restrict__ out_features,
    float* __restrict__ out_probs) {
    int sub = threadIdx.x >> 7, t = threadIdx.x & 127;
    int n = blockIdx.x * 4 + sub;
    __shared__ float p[4][L + 1];
    __shared__ int idx[4][L];
    int V = lengths[n];
    if (V < 1) V = 1;
    if (t < L) idx[sub][t] = s2c[n * L + t];
    if (t == 0) {
        const float* srow = scores + n * (L + 1);
        float m = srow[L];
        for (int l = 0; l < V; ++l) m = fmaxf(m, srow[l]);
        float sum = 0.f;
        for (int l = 0; l < V; ++l) { float e = expf(srow[l] - m); p[sub][l] = e; sum += e; }
        for (int l = V; l < L; ++l) p[sub][l] = 0.f;
        float es = expf(srow[L] - m); p[sub][L] = es; sum += es;
        float inv = 1.f / sum;
        for (int l = 0; l <= L; ++l) p[sub][l] *= inv;
    }
    __syncthreads();
    if (t <= L) out_probs[n * (L + 1) + t] = p[sub][t];
    const float4* kn = (const float4*)know;
    float4 acc;
    {
        float ps = p[sub][L];
        float4 sv = ((const float4*)sentinel)[n * 128 + t];
        acc.x = ps * sv.x; acc.y = ps * sv.y; acc.z = ps * sv.z; acc.w = ps * sv.w;
    }
    int l = 0;
    for (; l + 2 <= V; l += 2) {
        float p0 = p[sub][l], p1 = p[sub][l + 1];
        float4 v0 = kn[idx[sub][l] * 128 + t];
        float4 v1 = kn[idx[sub][l + 1] * 128 + t];
        acc.x = fmaf(p0, v0.x, acc.x); acc.y = fmaf(p0, v0.y, acc.y);
        acc.z = fmaf(p0, v0.z, acc.z); acc.w = fmaf(p0, v0.w, acc.w);
        acc.x = fmaf(p1, v1.x, acc.x); acc.y = fmaf(p1, v1.y, acc.y);
        acc.z = fmaf(p1, v1.z, acc.z); acc.w = fmaf(p1, v1.w, acc.w);
    }
    if (l < V) {
        float p0 = p[sub][l];
        float4 v0 = kn[idx[sub][l] * 128 + t];
        acc.x = fmaf(p0, v0.x, acc.x); acc.y = fmaf(p0, v0.y, acc.y);
        acc.z = fmaf(p0, v0.z, acc.z); acc.w = fmaf(p0, v0.w, acc.w);
    }
    ((float4*)out_features)[n * 128 + t] = acc;
}

extern "C" void kernel_launch(void* const* d_in, const int* in_sizes, int n_in,
                              void* d_out, int out_size, void* d_ws, size_t ws_size,
                              hipStream_t stream) {
    const float* span = (const float*)d_in[0];   // (256, 512)
    const float* know = (const float*)d_in[1];   // (1024, 512)
    const int* s2c = (const int*)d_in[2];        // (256, 64)
    const int* lengths = (const int*)d_in[3];    // (256,)
    const float* Ws = (const float*)d_in[4];     // (512, 512)
    const float* bs = (const float*)d_in[5];     // (512,)
    const float* W1 = (const float*)d_in[6];     // (1024, 500)
    const float* b1 = (const float*)d_in[7];     // (500,)
    const float* W2 = (const float*)d_in[8];     // (500, 500)
    const float* b2 = (const float*)d_in[9];     // (500,)
    const float* W3 = (const float*)d_in[10];    // (500, 1)
    const float* b3 = (const float*)d_in[11];    // (1,)

    float* ws = (float*)d_ws;
    float* spanb1 = ws;                               // 256*500
    float* parts = spanb1 + NSPAN * H;                // 1280*500 (know | sent)
    float* sentinel = parts + (KCON + NSPAN) * H;     // 256*512
    float* scores = sentinel + NSPAN * D;             // 256*65
    int* row_map = (int*)(scores + NSPAN * (L + 1));  // 16640
    int* Mptr = row_map + MMAX;                       // 1
    short* W2bf = (short*)(((uintptr_t)(Mptr + 1) + 63) & ~(uintptr_t)63);  // 512x512 bf16

    float* out_features = (float*)d_out;              // 256*512
    float* out_probs = out_features + NSPAN * D;      // 256*65

    k_parts<<<257, 512, 0, stream>>>(span, know, s2c, lengths, Ws, bs, W1, b1,
                                     W2, spanb1, parts, sentinel, row_map, Mptr,
                                     W2bf);
    k_scores<<<MMAX / RT, 256, 0, stream>>>(row_map, Mptr, spanb1, parts,
                                            W2bf, b2, W3, b3, scores);
    k_out<<<NSPAN / 4, 512, 0, stream>>>(s2c, lengths, scores, know, sentinel,
                                         out_features, out_probs);
}

// Round 7
// 144.674 us; speedup vs baseline: 2.2417x; 1.3858x over previous
//
#include <hip/hip_runtime.h>
#include <math.h>
#include <stdint.h>

#define D 512
#define H 500
#define NSPAN 256
#define KCON 1024
#define L 64
#define RT 32                   // flat rows per k_scores block
#define MMAX (NSPAN * (L + 1))  // 16640 flat-row upper bound

typedef __attribute__((ext_vector_type(8))) short short8;
typedef __attribute__((ext_vector_type(4))) float floatx4;

__device__ __forceinline__ short f2bf(float f) {   // RNE f32->bf16
    unsigned u = __builtin_bit_cast(unsigned, f);
    return (short)((u + 0x7fffu + ((u >> 16) & 1u)) >> 16);
}

// ------- Kernel 0: weight swizzles (bf16 B-frag layout) + planner ----------
// Slot s holds B[k0..k0+7][n] with kq=s&3, n=(s>>2)&511, kb=s>>11, k0=kb*32+kq*8.
// b>>6: 0=W2, 1=Ws, 2=W1a, 3=W1b; b==256: planner.
__global__ __launch_bounds__(512) void k_prep(
    const float* __restrict__ W2, const float* __restrict__ Ws,
    const float* __restrict__ W1, const int* __restrict__ s2c,
    const int* __restrict__ lengths,
    short* __restrict__ W2bf, short* __restrict__ Wsbf,
    short* __restrict__ W1abf, short* __restrict__ W1bbf,
    int* __restrict__ row_map, int* __restrict__ Mptr) {
    int b = blockIdx.x, tid = threadIdx.x;

    if (b == 256) {   // ---- planner ----
        __shared__ int sc[NSPAN];
        int R = 0;
        if (tid < NSPAN) {
            int V = lengths[tid];
            if (V < 1) V = 1;
            R = V + 1;
            sc[tid] = R;
        }
        __syncthreads();
        for (int s = 1; s < NSPAN; s <<= 1) {
            int v = 0;
            if (tid < NSPAN && tid >= s) v = sc[tid - s];
            __syncthreads();
            if (tid < NSPAN) sc[tid] += v;
            __syncthreads();
        }
        if (tid < NSPAN) {
            int start = sc[tid] - R;
            int V = R - 1;
            for (int l = 0; l < V; ++l)
                row_map[start + l] = (s2c[tid * L + l] << 16) | (tid << 8) | l;
            row_map[start + V] = ((KCON + tid) << 16) | (tid << 8) | L;
            if (tid == NSPAN - 1) Mptr[0] = sc[NSPAN - 1];
        }
        return;
    }

    int mb = b >> 6;
    int s = (b & 63) * 512 + tid;
    int kq = s & 3, n = (s >> 2) & 511, kb = s >> 11;
    int k0 = kb * 32 + kq * 8;
    short8 v8;
    #pragma unroll
    for (int i = 0; i < 8; ++i) {
        int k = k0 + i;
        float v;
        if (mb == 0)      v = (k < H && n < H) ? W2[k * H + n] : 0.f;
        else if (mb == 1) v = Ws[k * D + n];
        else if (mb == 2) v = (n < H) ? W1[k * H + n] : 0.f;
        else              v = (n < H) ? W1[(D + k) * H + n] : 0.f;
        v8[i] = f2bf(v);
    }
    short* dst = (mb == 0) ? W2bf : (mb == 1) ? Wsbf : (mb == 2) ? W1abf : W1bbf;
    ((short8*)dst)[s] = v8;
}

// ------- Kernel 1: MFMA parts GEMMs + sentinel chain -----------------------
// 256 thr = 4 waves. b<32: span@W1a+b1 (16 rows x half-N); b<160: know@W1b;
// b>=160: sentinel chain, full-N: relu(span@Ws+bs) -> sentinel, LDS re-stage
// to A-frag layout, @W1b -> parts[1024+].
__global__ __launch_bounds__(256) void k_mm1(
    const float* __restrict__ span, const float* __restrict__ know,
    const float* __restrict__ bs, const float* __restrict__ b1,
    const short* __restrict__ Wsbf, const short* __restrict__ W1abf,
    const short* __restrict__ W1bbf,
    float* __restrict__ spanb1, float* __restrict__ parts,
    float* __restrict__ sentinel) {
    __shared__ __align__(16) short Asw[16 * 512];   // 16 KB
    int b = blockIdx.x, tid = threadIdx.x;
    int wv = tid >> 6, ln = tid & 63;
    int nl = ln & 15, kq = ln >> 4;
    int aoff = nl * 32 + kq * 8;

    if (b < 160) {            // ---- span / know: 16 rows x 256 cols ----
        int rg, nh;
        const float* src;
        const short8* B;
        bool is_span = (b < 32);
        if (is_span) { rg = b >> 1; nh = b & 1; src = span + rg * 16 * D;
                       B = (const short8*)W1abf; }
        else { int bb = b - 32; rg = bb >> 1; nh = bb & 1; src = know + rg * 16 * D;
               B = (const short8*)W1bbf; }
        {   // stage A: thread = (row r, k-panel kb), 32 contiguous bf16
            int r = tid >> 4, kb = tid & 15;
            const float* sp = src + r * D + kb * 32;
            short* dst = &Asw[kb * 512 + r * 32];
            #pragma unroll
            for (int i = 0; i < 32; ++i) dst[i] = f2bf(sp[i]);
        }
        __syncthreads();
        floatx4 acc[4];
        #pragma unroll
        for (int t = 0; t < 4; ++t) acc[t] = (floatx4){0.f, 0.f, 0.f, 0.f};
        int tb = nh * 16 + wv * 4;
        int boff = tb * 64 + nl * 4 + kq;
        #pragma unroll 1
        for (int kb = 0; kb < 16; ++kb) {
            short8 a = *(const short8*)&Asw[kb * 512 + aoff];
            short8 bf[4];
            #pragma unroll
            for (int t = 0; t < 4; ++t) bf[t] = B[kb * 2048 + boff + t * 64];
            #pragma unroll
            for (int t = 0; t < 4; ++t)
                acc[t] = __builtin_amdgcn_mfma_f32_16x16x32_bf16(a, bf[t], acc[t], 0, 0, 0);
        }
        #pragma unroll
        for (int t = 0; t < 4; ++t) {
            int col = (tb + t) * 16 + nl;
            if (col < H) {
                if (is_span) {
                    float bc = b1[col];
                    #pragma unroll
                    for (int r = 0; r < 4; ++r)
                        spanb1[(size_t)(rg * 16 + kq * 4 + r) * H + col] = acc[t][r] + bc;
                } else {
                    #pragma unroll
                    for (int r = 0; r < 4; ++r)
                        parts[(size_t)(rg * 16 + kq * 4 + r) * H + col] = acc[t][r];
                }
            }
        }
        return;
    }

    // ---- sentinel chain: 16 rows x full 512 cols, two chained GEMMs ----
    int rg = b - 160;
    const float* src = span + rg * 16 * D;
    {
        int r = tid >> 4, kb = tid & 15;
        const float* sp = src + r * D + kb * 32;
        short* dst = &Asw[kb * 512 + r * 32];
        #pragma unroll
        for (int i = 0; i < 32; ++i) dst[i] = f2bf(sp[i]);
    }
    __syncthreads();
    floatx4 acc[8];
    #pragma unroll
    for (int t = 0; t < 8; ++t) acc[t] = (floatx4){0.f, 0.f, 0.f, 0.f};
    int boff = wv * 8 * 64 + nl * 4 + kq;
    const short8* B1 = (const short8*)Wsbf;
    #pragma unroll 1
    for (int kb = 0; kb < 16; ++kb) {
        short8 a = *(const short8*)&Asw[kb * 512 + aoff];
        short8 bf[8];
        #pragma unroll
        for (int t = 0; t < 8; ++t) bf[t] = B1[kb * 2048 + boff + t * 64];
        #pragma unroll
        for (int t = 0; t < 8; ++t)
            acc[t] = __builtin_amdgcn_mfma_f32_16x16x32_bf16(a, bf[t], acc[t], 0, 0, 0);
    }
    float vbuf[8][4];
    #pragma unroll
    for (int t = 0; t < 8; ++t) {
        int col = (wv * 8 + t) * 16 + nl;
        float bc = bs[col];
        #pragma unroll
        for (int r = 0; r < 4; ++r) {
            float v = fmaxf(acc[t][r] + bc, 0.f);
            vbuf[t][r] = v;
            sentinel[(size_t)(rg * 16 + kq * 4 + r) * D + col] = v;
        }
    }
    __syncthreads();          // Asw stage-1 reads done
    #pragma unroll
    for (int t = 0; t < 8; ++t) {
        int col = (wv * 8 + t) * 16 + nl;
        short* d = &Asw[(col >> 5) * 512 + (col & 31)];
        #pragma unroll
        for (int r = 0; r < 4; ++r) d[(kq * 4 + r) * 32] = f2bf(vbuf[t][r]);
    }
    __syncthreads();
    const short8* B2 = (const short8*)W1bbf;
    #pragma unroll
    for (int t = 0; t < 8; ++t) acc[t] = (floatx4){0.f, 0.f, 0.f, 0.f};
    #pragma unroll 1
    for (int kb = 0; kb < 16; ++kb) {
        short8 a = *(const short8*)&Asw[kb * 512 + aoff];
        short8 bf[8];
        #pragma unroll
        for (int t = 0; t < 8; ++t) bf[t] = B2[kb * 2048 + boff + t * 64];
        #pragma unroll
        for (int t = 0; t < 8; ++t)
            acc[t] = __builtin_amdgcn_mfma_f32_16x16x32_bf16(a, bf[t], acc[t], 0, 0, 0);
    }
    #pragma unroll
    for (int t = 0; t < 8; ++t) {
        int col = (wv * 8 + t) * 16 + nl;
        if (col < H) {
            #pragma unroll
            for (int r = 0; r < 4; ++r)
                parts[(size_t)(KCON + rg * 16 + kq * 4 + r) * H + col] = acc[t][r];
        }
    }
}

// ---- Kernel 2: MFMA score GEMM: C[32 x 512] = h1[32 x 512] @ W2bf ---------
// 512 thr = 8 waves: (row-half hh = wv>>2) x (n-quarter q = wv&3, 8 tiles).
__global__ __launch_bounds__(512) void k_scores(
    const int* __restrict__ row_map, const int* __restrict__ Mptr,
    const float* __restrict__ spanb1, const float* __restrict__ parts,
    const short* __restrict__ W2bf, const float* __restrict__ b2,
    const float* __restrict__ W3, const float* __restrict__ b3,
    float* __restrict__ scores) {
    int tid = threadIdx.x;
    int t0 = blockIdx.x * RT;
    int M = Mptr[0];
    if (t0 >= M) return;
    int rc = min(RT, M - t0);

    __shared__ __align__(16) short Asw[16 * 1024];  // 32 KB: kb*1024 + m*32 + k
    __shared__ float red[8][16];
    __shared__ int rinfo[RT];
    if (tid < RT) rinfo[tid] = row_map[t0 + min(tid, rc - 1)];
    __syncthreads();

    {   // stage h1 -> Asw: thread = (row r: 32, k-panel kb: 16)
        int r = tid >> 4, kb = tid & 15;
        int e = rinfo[r];
        const float* src = parts + (size_t)(e >> 16) * H;
        const float* spn = spanb1 + (size_t)((e >> 8) & 0xff) * H;
        short* dst = &Asw[kb * 1024 + r * 32];
        int k0 = kb * 32;
        #pragma unroll
        for (int i = 0; i < 32; ++i) {
            int k = k0 + i;
            float v = (k < H) ? fmaxf(spn[k] + src[k], 0.f) : 0.f;
            dst[i] = f2bf(v);
        }
    }
    __syncthreads();

    int wv = tid >> 6, ln = tid & 63;
    int nl = ln & 15, kq = ln >> 4;
    int q = wv & 3, hh = wv >> 2;
    int aoff = hh * 512 + nl * 32 + kq * 8;
    int boff = q * 8 * 64 + nl * 4 + kq;
    floatx4 acc[8];
    #pragma unroll
    for (int t = 0; t < 8; ++t) acc[t] = (floatx4){0.f, 0.f, 0.f, 0.f};

    const short8* B = (const short8*)W2bf;
    #pragma unroll 1
    for (int kb = 0; kb < 16; ++kb) {
        short8 a = *(const short8*)&Asw[kb * 1024 + aoff];
        short8 bfr[8];
        #pragma unroll
        for (int t = 0; t < 8; ++t) bfr[t] = B[kb * 2048 + boff + t * 64];
        #pragma unroll
        for (int t = 0; t < 8; ++t)
            acc[t] = __builtin_amdgcn_mfma_f32_16x16x32_bf16(a, bfr[t], acc[t], 0, 0, 0);
    }

    // epilogue: per-row partial = sum_cols relu(h2 + b2) * W3
    float vsum[4] = {0.f, 0.f, 0.f, 0.f};
    #pragma unroll
    for (int t = 0; t < 8; ++t) {
        int col = (q * 8 + t) * 16 + nl;
        float b2c = (col < H) ? b2[col] : 0.f;
        float w3c = (col < H) ? W3[col] : 0.f;
        #pragma unroll
        for (int r = 0; r < 4; ++r)
            vsum[r] += fmaxf(acc[t][r] + b2c, 0.f) * w3c;
    }
    #pragma unroll
    for (int r = 0; r < 4; ++r) {
        float v = vsum[r];
        v += __shfl_xor(v, 1, 64);
        v += __shfl_xor(v, 2, 64);
        v += __shfl_xor(v, 4, 64);
        v += __shfl_xor(v, 8, 64);
        vsum[r] = v;
    }
    if (nl == 0) {
        #pragma unroll
        for (int r = 0; r < 4; ++r) red[wv][kq * 4 + r] = vsum[r];
    }
    __syncthreads();
    if (tid < rc) {
        int m = tid, h2 = m >> 4, rl = m & 15;
        float s = red[h2 * 4 + 0][rl] + red[h2 * 4 + 1][rl]
                + red[h2 * 4 + 2][rl] + red[h2 * 4 + 3][rl] + b3[0];
        int e = rinfo[m];
        int n = (e >> 8) & 0xff, lpos = e & 0xff;
        scores[n * (L + 1) + lpos] = s;
    }
}

// -------- Kernel 3: masked softmax + probs out + feature gather ------------
// 256 blocks (1 span), 512 thr: wave-parallel softmax; l-range split 4-way.
__global__ __launch_bounds__(512) void k_out(
    const int* __restrict__ s2c, const int* __restrict__ lengths,
    const float* __restrict__ scores, const float* __restrict__ know,
    const float* __restrict__ sentinel, float* __restrict__ out_features,
    float* __restrict__ out_probs) {
    int n = blockIdx.x, tid = threadIdx.x;
    __shared__ float p[L + 1];
    __shared__ int idx[L];
    __shared__ __align__(16) float4 partb[4][128];   // 8 KB
    int V = lengths[n];
    if (V < 1) V = 1;
    if (tid < L) idx[tid] = s2c[n * L + tid];
    if (tid < 64) {
        const float* srow = scores + n * (L + 1);
        float sL = srow[L];
        float val = (tid < V) ? srow[tid] : -1e30f;
        float m = val;
        #pragma unroll
        for (int off = 32; off > 0; off >>= 1) m = fmaxf(m, __shfl_xor(m, off, 64));
        m = fmaxf(m, sL);
        float e = (tid < V) ? expf(val - m) : 0.f;
        float s = e;
        #pragma unroll
        for (int off = 32; off > 0; off >>= 1) s += __shfl_xor(s, off, 64);
        float eL = expf(sL - m);
        float inv = 1.f / (s + eL);
        p[tid] = e * inv;
        if (tid == 0) p[L] = eL * inv;
    }
    __syncthreads();
    if (tid <= L) out_probs[n * (L + 1) + tid] = p[tid];
    int sub = tid >> 7, c = tid & 127;
    float4 acc = {0.f, 0.f, 0.f, 0.f};
    if (sub == 0) {
        float ps = p[L];
        float4 sv = ((const float4*)sentinel)[n * 128 + c];
        acc.x = ps * sv.x; acc.y = ps * sv.y; acc.z = ps * sv.z; acc.w = ps * sv.w;
    }
    const float4* kn = (const float4*)know;
    for (int l = sub; l < V; l += 4) {
        float pl = p[l];
        float4 v = kn[idx[l] * 128 + c];
        acc.x = fmaf(pl, v.x, acc.x); acc.y = fmaf(pl, v.y, acc.y);
        acc.z = fmaf(pl, v.z, acc.z); acc.w = fmaf(pl, v.w, acc.w);
    }
    partb[sub][c] = acc;
    __syncthreads();
    if (tid < 128) {
        float4 a0 = partb[0][tid], a1 = partb[1][tid];
        float4 a2 = partb[2][tid], a3 = partb[3][tid];
        float4 o;
        o.x = a0.x + a1.x + a2.x + a3.x;
        o.y = a0.y + a1.y + a2.y + a3.y;
        o.z = a0.z + a1.z + a2.z + a3.z;
        o.w = a0.w + a1.w + a2.w + a3.w;
        ((float4*)out_features)[n * 128 + tid] = o;
    }
}

extern "C" void kernel_launch(void* const* d_in, const int* in_sizes, int n_in,
                              void* d_out, int out_size, void* d_ws, size_t ws_size,
                              hipStream_t stream) {
    const float* span = (const float*)d_in[0];   // (256, 512)
    const float* know = (const float*)d_in[1];   // (1024, 512)
    const int* s2c = (const int*)d_in[2];        // (256, 64)
    const int* lengths = (const int*)d_in[3];    // (256,)
    const float* Ws = (const float*)d_in[4];     // (512, 512)
    const float* bs = (const float*)d_in[5];     // (512,)
    const float* W1 = (const float*)d_in[6];     // (1024, 500)
    const float* b1 = (const float*)d_in[7];     // (500,)
    const float* W2 = (const float*)d_in[8];     // (500, 500)
    const float* b2 = (const float*)d_in[9];     // (500,)
    const float* W3 = (const float*)d_in[10];    // (500, 1)
    const float* b3 = (const float*)d_in[11];    // (1,)

    float* ws = (float*)d_ws;
    float* spanb1 = ws;                               // 256*500
    float* parts = spanb1 + NSPAN * H;                // 1280*500 (know | sent)
    float* sentinel = parts + (KCON + NSPAN) * H;     // 256*512
    float* scores = sentinel + NSPAN * D;             // 256*65
    int* row_map = (int*)(scores + NSPAN * (L + 1));  // 16640
    int* Mptr = row_map + MMAX;                       // 1
    short* W2bf = (short*)(((uintptr_t)(Mptr + 1) + 63) & ~(uintptr_t)63);
    short* Wsbf = W2bf + 512 * 512;
    short* W1abf = Wsbf + 512 * 512;
    short* W1bbf = W1abf + 512 * 512;

    float* out_features = (float*)d_out;              // 256*512
    float* out_probs = out_features + NSPAN * D;      // 256*65

    k_prep<<<257, 512, 0, stream>>>(W2, Ws, W1, s2c, lengths,
                                    W2bf, Wsbf, W1abf, W1bbf, row_map, Mptr);
    k_mm1<<<176, 256, 0, stream>>>(span, know, bs, b1, Wsbf, W1abf, W1bbf,
                                   spanb1, parts, sentinel);
    k_scores<<<MMAX / RT, 512, 0, stream>>>(row_map, Mptr, spanb1, parts,
                                            W2bf, b2, W3, b3, scores);
    k_out<<<NSPAN, 512, 0, stream>>>(s2c, lengths, scores, know, sentinel,
                                     out_features, out_probs);
}

// Round 8
// 126.653 us; speedup vs baseline: 2.5606x; 1.1423x over previous
//
#include <hip/hip_runtime.h>
#include <math.h>
#include <stdint.h>

#define D 512
#define H 500
#define NSPAN 256
#define KCON 1024
#define L 64

typedef __attribute__((ext_vector_type(8))) short short8;
typedef __attribute__((ext_vector_type(4))) float floatx4;

__device__ __forceinline__ short f2bf(float f) {   // RNE f32->bf16
    unsigned u = __builtin_bit_cast(unsigned, f);
    return (short)((u + 0x7fffu + ((u >> 16) & 1u)) >> 16);
}

// ------- Kernel 0: weight swizzles into bf16 B-frag layout -----------------
// Slot s holds B[k0..k0+7][n], kq=s&3, n=(s>>2)&511, kb=s>>11, k0=kb*32+kq*8.
// b>>6 selects: 0=W2, 1=Ws, 2=W1a, 3=W1b.
__global__ __launch_bounds__(512) void k_prep(
    const float* __restrict__ W2, const float* __restrict__ Ws,
    const float* __restrict__ W1,
    short* __restrict__ W2bf, short* __restrict__ Wsbf,
    short* __restrict__ W1abf, short* __restrict__ W1bbf) {
    int b = blockIdx.x, tid = threadIdx.x;
    int mb = b >> 6;
    int s = (b & 63) * 512 + tid;
    int kq = s & 3, n = (s >> 2) & 511, kb = s >> 11;
    int k0 = kb * 32 + kq * 8;
    short8 v8;
    #pragma unroll
    for (int i = 0; i < 8; ++i) {
        int k = k0 + i;
        float v;
        if (mb == 0)      v = (k < H && n < H) ? W2[k * H + n] : 0.f;
        else if (mb == 1) v = Ws[k * D + n];
        else if (mb == 2) v = (n < H) ? W1[k * H + n] : 0.f;
        else              v = (n < H) ? W1[(D + k) * H + n] : 0.f;
        v8[i] = f2bf(v);
    }
    short* dst = (mb == 0) ? W2bf : (mb == 1) ? Wsbf : (mb == 2) ? W1abf : W1bbf;
    ((short8*)dst)[s] = v8;
}

// ------- Kernel 1: MFMA parts GEMMs + sentinel chain -----------------------
// 256 thr = 4 waves. b<32: span@W1a+b1 (16 rows x half-N); b<160: know@W1b;
// b>=160: sentinel chain (relu(span@Ws+bs) -> sentinel, restage, @W1b).
__global__ __launch_bounds__(256) void k_mm1(
    const float* __restrict__ span, const float* __restrict__ know,
    const float* __restrict__ bs, const float* __restrict__ b1,
    const short* __restrict__ Wsbf, const short* __restrict__ W1abf,
    const short* __restrict__ W1bbf,
    float* __restrict__ spanb1, float* __restrict__ parts,
    float* __restrict__ sentinel) {
    __shared__ __align__(16) short Asw[16 * 512];   // 16 KB
    int b = blockIdx.x, tid = threadIdx.x;
    int wv = tid >> 6, ln = tid & 63;
    int nl = ln & 15, kq = ln >> 4;
    int aoff = nl * 32 + kq * 8;

    if (b < 160) {            // ---- span / know: 16 rows x 256 cols ----
        int rg, nh;
        const float* src;
        const short8* B;
        bool is_span = (b < 32);
        if (is_span) { rg = b >> 1; nh = b & 1; src = span + rg * 16 * D;
                       B = (const short8*)W1abf; }
        else { int bb = b - 32; rg = bb >> 1; nh = bb & 1; src = know + rg * 16 * D;
               B = (const short8*)W1bbf; }
        {   // stage A: thread = (row r, k-panel kb), 32 contiguous bf16
            int r = tid >> 4, kb = tid & 15;
            const float* sp = src + r * D + kb * 32;
            short* dst = &Asw[kb * 512 + r * 32];
            #pragma unroll
            for (int i = 0; i < 32; ++i) dst[i] = f2bf(sp[i]);
        }
        __syncthreads();
        floatx4 acc[4];
        #pragma unroll
        for (int t = 0; t < 4; ++t) acc[t] = (floatx4){0.f, 0.f, 0.f, 0.f};
        int tb = nh * 16 + wv * 4;
        int boff = tb * 64 + nl * 4 + kq;
        #pragma unroll 1
        for (int kb = 0; kb < 16; ++kb) {
            short8 a = *(const short8*)&Asw[kb * 512 + aoff];
            short8 bf[4];
            #pragma unroll
            for (int t = 0; t < 4; ++t) bf[t] = B[kb * 2048 + boff + t * 64];
            #pragma unroll
            for (int t = 0; t < 4; ++t)
                acc[t] = __builtin_amdgcn_mfma_f32_16x16x32_bf16(a, bf[t], acc[t], 0, 0, 0);
        }
        #pragma unroll
        for (int t = 0; t < 4; ++t) {
            int col = (tb + t) * 16 + nl;
            if (col < H) {
                if (is_span) {
                    float bc = b1[col];
                    #pragma unroll
                    for (int r = 0; r < 4; ++r)
                        spanb1[(size_t)(rg * 16 + kq * 4 + r) * H + col] = acc[t][r] + bc;
                } else {
                    #pragma unroll
                    for (int r = 0; r < 4; ++r)
                        parts[(size_t)(rg * 16 + kq * 4 + r) * H + col] = acc[t][r];
                }
            }
        }
        return;
    }

    // ---- sentinel chain: 16 rows x full 512 cols, two chained GEMMs ----
    int rg = b - 160;
    const float* src = span + rg * 16 * D;
    {
        int r = tid >> 4, kb = tid & 15;
        const float* sp = src + r * D + kb * 32;
        short* dst = &Asw[kb * 512 + r * 32];
        #pragma unroll
        for (int i = 0; i < 32; ++i) dst[i] = f2bf(sp[i]);
    }
    __syncthreads();
    floatx4 acc[8];
    #pragma unroll
    for (int t = 0; t < 8; ++t) acc[t] = (floatx4){0.f, 0.f, 0.f, 0.f};
    int boff = wv * 8 * 64 + nl * 4 + kq;
    const short8* B1 = (const short8*)Wsbf;
    #pragma unroll 1
    for (int kb = 0; kb < 16; ++kb) {
        short8 a = *(const short8*)&Asw[kb * 512 + aoff];
        short8 bf[8];
        #pragma unroll
        for (int t = 0; t < 8; ++t) bf[t] = B1[kb * 2048 + boff + t * 64];
        #pragma unroll
        for (int t = 0; t < 8; ++t)
            acc[t] = __builtin_amdgcn_mfma_f32_16x16x32_bf16(a, bf[t], acc[t], 0, 0, 0);
    }
    float vbuf[8][4];
    #pragma unroll
    for (int t = 0; t < 8; ++t) {
        int col = (wv * 8 + t) * 16 + nl;
        float bc = bs[col];
        #pragma unroll
        for (int r = 0; r < 4; ++r) {
            float v = fmaxf(acc[t][r] + bc, 0.f);
            vbuf[t][r] = v;
            sentinel[(size_t)(rg * 16 + kq * 4 + r) * D + col] = v;
        }
    }
    __syncthreads();          // Asw stage-1 reads done
    #pragma unroll
    for (int t = 0; t < 8; ++t) {
        int col = (wv * 8 + t) * 16 + nl;
        short* d = &Asw[(col >> 5) * 512 + (col & 31)];
        #pragma unroll
        for (int r = 0; r < 4; ++r) d[(kq * 4 + r) * 32] = f2bf(vbuf[t][r]);
    }
    __syncthreads();
    const short8* B2 = (const short8*)W1bbf;
    #pragma unroll
    for (int t = 0; t < 8; ++t) acc[t] = (floatx4){0.f, 0.f, 0.f, 0.f};
    #pragma unroll 1
    for (int kb = 0; kb < 16; ++kb) {
        short8 a = *(const short8*)&Asw[kb * 512 + aoff];
        short8 bf[8];
        #pragma unroll
        for (int t = 0; t < 8; ++t) bf[t] = B2[kb * 2048 + boff + t * 64];
        #pragma unroll
        for (int t = 0; t < 8; ++t)
            acc[t] = __builtin_amdgcn_mfma_f32_16x16x32_bf16(a, bf[t], acc[t], 0, 0, 0);
    }
    #pragma unroll
    for (int t = 0; t < 8; ++t) {
        int col = (wv * 8 + t) * 16 + nl;
        if (col < H) {
            #pragma unroll
            for (int r = 0; r < 4; ++r)
                parts[(size_t)(KCON + rg * 16 + kq * 4 + r) * H + col] = acc[t][r];
        }
    }
}

// ---- Kernel 2: fused per-span scores + softmax + probs + feature gather ---
// grid 256 (1 span/block), 512 thr = 8 waves. R = V+1 <= 64 rows staged once
// (4 M-tiles bf16 in LDS); W2bf streamed exactly once per block; then the
// whole epilogue (softmax + weighted gather) runs in-block.
__global__ __launch_bounds__(512) void k_fused(
    const int* __restrict__ s2c, const int* __restrict__ lengths,
    const float* __restrict__ spanb1, const float* __restrict__ parts,
    const float* __restrict__ sentinel, const short* __restrict__ W2bf,
    const float* __restrict__ b2, const float* __restrict__ W3,
    const float* __restrict__ b3, const float* __restrict__ know,
    float* __restrict__ out_features, float* __restrict__ out_probs) {
    int n = blockIdx.x, tid = threadIdx.x;
    int V = lengths[n];
    V = (V < 1) ? 1 : ((V > 63) ? 63 : V);
    int R = V + 1;                 // concepts 0..V-1, sentinel at row V
    int nmt = (R + 15) >> 4;       // M-tiles (1..4)

    __shared__ __align__(16) short Asw[16 * 2048];   // 64 KB: kb*2048+mt*512+m*32+k
    __shared__ float red[8][64];                     // 2 KB
    __shared__ float sscore[64];
    __shared__ float p[L + 1];
    __shared__ int idx[L];
    __shared__ __align__(16) float4 partb[4][128];   // 8 KB

    if (tid < L) idx[tid] = s2c[n * L + tid];

    {   // stage h1 rows -> A-frag LDS; thread = (row r: 32, k-panel kb: 16)
        int r = tid >> 4, kb = tid & 15, k0 = kb * 32;
        const float* spn = spanb1 + (size_t)n * H;
        #pragma unroll
        for (int half = 0; half < 2; ++half) {
            int rr = r + half * 32;
            if (rr < nmt * 16) {
                int mt = rr >> 4, m = rr & 15;
                short* dst = &Asw[kb * 2048 + mt * 512 + m * 32];
                if (rr < R) {
                    const float* src = (rr < V)
                        ? parts + (size_t)s2c[n * L + rr] * H
                        : parts + (size_t)(KCON + n) * H;
                    const float4* s4 = (const float4*)(spn + k0);
                    const float4* r4 = (const float4*)(src + k0);
                    #pragma unroll
                    for (int g = 0; g < 8; ++g) {
                        if (k0 + g * 4 < H) {     // 500 = 125 float4, clean split
                            float4 a = s4[g], c = r4[g];
                            dst[g * 4 + 0] = f2bf(fmaxf(a.x + c.x, 0.f));
                            dst[g * 4 + 1] = f2bf(fmaxf(a.y + c.y, 0.f));
                            dst[g * 4 + 2] = f2bf(fmaxf(a.z + c.z, 0.f));
                            dst[g * 4 + 3] = f2bf(fmaxf(a.w + c.w, 0.f));
                        } else {
                            dst[g * 4 + 0] = 0; dst[g * 4 + 1] = 0;
                            dst[g * 4 + 2] = 0; dst[g * 4 + 3] = 0;
                        }
                    }
                } else {
                    #pragma unroll
                    for (int g = 0; g < 8; ++g)
                        *(short4*)&dst[g * 4] = (short4){0, 0, 0, 0};
                }
            }
        }
    }
    __syncthreads();

    int wv = tid >> 6, ln = tid & 63;
    int nl = ln & 15, kq = ln >> 4;
    int aoffb = nl * 32 + kq * 8;
    int boffb = wv * 4 * 64 + nl * 4 + kq;   // wave owns 64-col slab (4 n-tiles)
    floatx4 acc[4][4];
    #pragma unroll
    for (int mt = 0; mt < 4; ++mt)
        #pragma unroll
        for (int t = 0; t < 4; ++t) acc[mt][t] = (floatx4){0.f, 0.f, 0.f, 0.f};

    const short8* B = (const short8*)W2bf;
    #pragma unroll 1
    for (int kb = 0; kb < 16; ++kb) {
        short8 bfr[4];
        #pragma unroll
        for (int t = 0; t < 4; ++t) bfr[t] = B[kb * 2048 + boffb + t * 64];
        #pragma unroll
        for (int mt = 0; mt < 4; ++mt) {
            if (mt < nmt) {
                short8 a = *(const short8*)&Asw[kb * 2048 + mt * 512 + aoffb];
                #pragma unroll
                for (int t = 0; t < 4; ++t)
                    acc[mt][t] = __builtin_amdgcn_mfma_f32_16x16x32_bf16(a, bfr[t], acc[mt][t], 0, 0, 0);
            }
        }
    }

    // epilogue: per-row partial = sum_cols relu(h2 + b2) * W3, reduce over nl
    float b2c[4], w3c[4];
    #pragma unroll
    for (int t = 0; t < 4; ++t) {
        int col = wv * 64 + t * 16 + nl;
        b2c[t] = (col < H) ? b2[col] : 0.f;
        w3c[t] = (col < H) ? W3[col] : 0.f;
    }
    #pragma unroll
    for (int mt = 0; mt < 4; ++mt) {
        if (mt < nmt) {
            #pragma unroll
            for (int r = 0; r < 4; ++r) {
                float v = fmaxf(acc[mt][0][r] + b2c[0], 0.f) * w3c[0]
                        + fmaxf(acc[mt][1][r] + b2c[1], 0.f) * w3c[1]
                        + fmaxf(acc[mt][2][r] + b2c[2], 0.f) * w3c[2]
                        + fmaxf(acc[mt][3][r] + b2c[3], 0.f) * w3c[3];
                v += __shfl_xor(v, 1, 64);
                v += __shfl_xor(v, 2, 64);
                v += __shfl_xor(v, 4, 64);
                v += __shfl_xor(v, 8, 64);
                if (nl == 0) red[wv][mt * 16 + kq * 4 + r] = v;
            }
        }
    }
    __syncthreads();
    if (tid < R) {
        float s = b3[0];
        #pragma unroll
        for (int w = 0; w < 8; ++w) s += red[w][tid];
        sscore[tid] = s;
    }
    __syncthreads();

    if (tid < 64) {   // wave-parallel masked softmax (sentinel at sscore[V])
        float sV = sscore[V];
        float val = (tid < V) ? sscore[tid] : -1e30f;
        float m = val;
        #pragma unroll
        for (int off = 32; off > 0; off >>= 1) m = fmaxf(m, __shfl_xor(m, off, 64));
        m = fmaxf(m, sV);
        float e = (tid < V) ? expf(val - m) : 0.f;
        float s = e;
        #pragma unroll
        for (int off = 32; off > 0; off >>= 1) s += __shfl_xor(s, off, 64);
        float eL = expf(sV - m);
        float inv = 1.f / (s + eL);
        p[tid] = e * inv;
        if (tid == 0) p[L] = eL * inv;
    }
    __syncthreads();
    if (tid <= L) out_probs[n * (L + 1) + tid] = p[tid];

    // feature gather: 4 l-groups x 128 float4-cols
    int sub = tid >> 7, c = tid & 127;
    float4 acc4 = {0.f, 0.f, 0.f, 0.f};
    if (sub == 0) {
        float ps = p[L];
        float4 sv = ((const float4*)sentinel)[n * 128 + c];
        acc4.x = ps * sv.x; acc4.y = ps * sv.y; acc4.z = ps * sv.z; acc4.w = ps * sv.w;
    }
    const float4* kn = (const float4*)know;
    for (int l = sub; l < V; l += 4) {
        float pl = p[l];
        float4 v = kn[idx[l] * 128 + c];
        acc4.x = fmaf(pl, v.x, acc4.x); acc4.y = fmaf(pl, v.y, acc4.y);
        acc4.z = fmaf(pl, v.z, acc4.z); acc4.w = fmaf(pl, v.w, acc4.w);
    }
    partb[sub][c] = acc4;
    __syncthreads();
    if (tid < 128) {
        float4 a0 = partb[0][tid], a1 = partb[1][tid];
        float4 a2 = partb[2][tid], a3 = partb[3][tid];
        float4 o;
        o.x = a0.x + a1.x + a2.x + a3.x;
        o.y = a0.y + a1.y + a2.y + a3.y;
        o.z = a0.z + a1.z + a2.z + a3.z;
        o.w = a0.w + a1.w + a2.w + a3.w;
        ((float4*)out_features)[n * 128 + tid] = o;
    }
}

extern "C" void kernel_launch(void* const* d_in, const int* in_sizes, int n_in,
                              void* d_out, int out_size, void* d_ws, size_t ws_size,
                              hipStream_t stream) {
    const float* span = (const float*)d_in[0];   // (256, 512)
    const float* know = (const float*)d_in[1];   // (1024, 512)
    const int* s2c = (const int*)d_in[2];        // (256, 64)
    const int* lengths = (const int*)d_in[3];    // (256,)
    const float* Ws = (const float*)d_in[4];     // (512, 512)
    const float* bs = (const float*)d_in[5];     // (512,)
    const float* W1 = (const float*)d_in[6];     // (1024, 500)
    const float* b1 = (const float*)d_in[7];     // (500,)
    const float* W2 = (const float*)d_in[8];     // (500, 500)
    const float* b2 = (const float*)d_in[9];     // (500,)
    const float* W3 = (const float*)d_in[10];    // (500, 1)
    const float* b3 = (const float*)d_in[11];    // (1,)

    float* ws = (float*)d_ws;
    float* spanb1 = ws;                               // 256*500
    float* parts = spanb1 + NSPAN * H;                // 1280*500 (know | sent)
    float* sentinel = parts + (KCON + NSPAN) * H;     // 256*512
    short* W2bf = (short*)(((uintptr_t)(sentinel + NSPAN * D) + 63) & ~(uintptr_t)63);
    short* Wsbf = W2bf + 512 * 512;
    short* W1abf = Wsbf + 512 * 512;
    short* W1bbf = W1abf + 512 * 512;

    float* out_features = (float*)d_out;              // 256*512
    float* out_probs = out_features + NSPAN * D;      // 256*65

    k_prep<<<256, 512, 0, stream>>>(W2, Ws, W1, W2bf, Wsbf, W1abf, W1bbf);
    k_mm1<<<176, 256, 0, stream>>>(span, know, bs, b1, Wsbf, W1abf, W1bbf,
                                   spanb1, parts, sentinel);
    k_fused<<<NSPAN, 512, 0, stream>>>(s2c, lengths, spanb1, parts, sentinel,
                                       W2bf, b2, W3, b3, know,
                                       out_features, out_probs);
}